// Round 1
// baseline (225.219 us; speedup 1.0000x reference)
//
#include <hip/hip_runtime.h>
#include <hip/hip_bf16.h>
#include <stdint.h>

// MMD: N=8192 rows (4096 source + 4096 target), D=256, fp32 in, scalar fp32 out.
// result = (1/4096^2) * sum_ij s_i s_j ksum(L2_ij),  s_i = +1 (i<4096) else -1
// ksum = sum_{m=0..4} exp(-L2/(bw0*2^m)) = w + w^2 + w^4 + w^8 + w^16, w=exp(-L2/(16 bw0))
// bw0 = [2N*sum(sq) - 2*sum_d colsum_d^2] / (N^2-N) / 4   (analytic sum(L2); clamp negligible)

#define NTOT 8192
#define DDIM 256
#define TILE 128
#define BK 32

typedef __bf16 bf16x8 __attribute__((ext_vector_type(8)));
typedef __bf16 bf16x4 __attribute__((ext_vector_type(4)));
typedef float f32x4 __attribute__((ext_vector_type(4)));

__device__ __forceinline__ void gl_lds16(const __bf16* g, __bf16* l) {
  __builtin_amdgcn_global_load_lds(
      (const __attribute__((address_space(1))) void*)g,
      (__attribute__((address_space(3))) void*)l, 16, 0, 0);
}

// ---- zero the fp64 accumulators ----
__global__ __launch_bounds__(64) void kzero(double* a) {
  if (threadIdx.x < 3) a[threadIdx.x] = 0.0;
}

// ---- convert fp32 -> bf16 buffer, per-row sq (from bf16-rounded values), sum(sq) ----
__global__ __launch_bounds__(256) void kconv(const float* __restrict__ src,
                                             const float* __restrict__ tgt,
                                             __bf16* __restrict__ Xbf,
                                             float* __restrict__ sq,
                                             double* __restrict__ accs) {
  int b = blockIdx.x;  // 2048 blocks, 4 rows each
  int t = threadIdx.x;
  const float* base = (b < 1024) ? (src + (size_t)b * 1024)
                                 : (tgt + (size_t)(b - 1024) * 1024);
  float4 v = ((const float4*)base)[t];
  __bf16 b0 = (__bf16)v.x, b1 = (__bf16)v.y, b2 = (__bf16)v.z, b3 = (__bf16)v.w;
  bf16x4 pk = {b0, b1, b2, b3};
  ((bf16x4*)(Xbf + (size_t)b * 1024))[t] = pk;
  float f0 = (float)b0, f1 = (float)b1, f2 = (float)b2, f3 = (float)b3;
  float s = f0 * f0 + f1 * f1 + f2 * f2 + f3 * f3;
  #pragma unroll
  for (int off = 32; off; off >>= 1) s += __shfl_down(s, off);
  int lane = t & 63;
  if (lane == 0) {
    int row = b * 4 + (t >> 6);  // one wave == one row (64 lanes * 4 elem = 256)
    sq[row] = s;
    atomicAdd(&accs[0], (double)s);
  }
}

// ---- column sums -> sum_d colsum_d^2 ----
__global__ __launch_bounds__(256) void kcol(const __bf16* __restrict__ Xbf,
                                            double* __restrict__ accs) {
  int d = blockIdx.x;  // 256 blocks, one per column
  int t = threadIdx.x;
  double cd = 0.0;
  #pragma unroll 4
  for (int m = 0; m < 32; ++m) {
    int r = t + 256 * m;
    cd += (double)(float)Xbf[(size_t)r * DDIM + d];
  }
  __shared__ double red[256];
  red[t] = cd;
  __syncthreads();
  for (int off = 128; off; off >>= 1) {
    if (t < off) red[t] += red[t + off];
    __syncthreads();
  }
  if (t == 0) {
    double c = red[0];
    atomicAdd(&accs[1], c * c);
  }
}

// ---- main: tiled symmetric Gram + fused kernel-sum epilogue + signed reduction ----
__global__ __launch_bounds__(256) void kgemm(const __bf16* __restrict__ Xbf,
                                             const float* __restrict__ sq,
                                             const double* __restrict__ accs,
                                             double* __restrict__ Sacc) {
  int tc = blockIdx.x, tr = blockIdx.y;
  if (tr > tc) return;  // symmetric: upper triangle only, off-diag tiles weighted 2x

  __shared__ alignas(16) __bf16 Ash[TILE * BK];
  __shared__ alignas(16) __bf16 Bsh[TILE * BK];
  __shared__ float sqR[TILE], sqC[TILE];
  __shared__ double red[4];

  int t = threadIdx.x;

  // bandwidth scale (every block recomputes from the two scalars; cheap)
  double ssq = accs[0], scol = accs[1];
  double sumL2 = 2.0 * 8192.0 * ssq - 2.0 * scol;
  double bw0 = sumL2 / (8192.0 * 8192.0 - 8192.0) / 4.0;
  float cs = (float)(-1.0 / (16.0 * bw0));

  if (t < 128) sqR[t] = sq[tr * TILE + t];
  else         sqC[t - 128] = sq[tc * TILE + (t - 128)];

  f32x4 acc[4][4];
  #pragma unroll
  for (int i = 0; i < 4; ++i)
    #pragma unroll
    for (int j = 0; j < 4; ++j) acc[i][j] = (f32x4){0.f, 0.f, 0.f, 0.f};

  const __bf16* Agbase = Xbf + (size_t)tr * TILE * DDIM;
  const __bf16* Bgbase = Xbf + (size_t)tc * TILE * DDIM;

  int wave = t >> 6, lane = t & 63;
  int mrow = lane & 15, kq = (lane >> 4) * 8;
  int wr = (wave & 1) * 64, wc = (wave >> 1) * 64;

  for (int it = 0; it < 8; ++it) {
    int k0 = it * BK;
    // stage 128x32 bf16 tiles for A and B: 512 16B-chunks each, 2 per thread.
    // LDS dest is chunk-contiguous => wave-uniform base + lane*16 (required).
    #pragma unroll
    for (int cc = 0; cc < 2; ++cc) {
      int c = t + cc * 256;
      int row = c >> 2, kc = c & 3;
      gl_lds16(Agbase + (size_t)row * DDIM + k0 + kc * 8, Ash + c * 8);
      gl_lds16(Bgbase + (size_t)row * DDIM + k0 + kc * 8, Bsh + c * 8);
    }
    __syncthreads();

    bf16x8 af[4], bfr[4];
    #pragma unroll
    for (int f = 0; f < 4; ++f) {
      af[f]  = *(const bf16x8*)&Ash[(wr + 16 * f + mrow) * BK + kq];
      bfr[f] = *(const bf16x8*)&Bsh[(wc + 16 * f + mrow) * BK + kq];
    }
    #pragma unroll
    for (int fr = 0; fr < 4; ++fr)
      #pragma unroll
      for (int fc = 0; fc < 4; ++fc)
        acc[fr][fc] = __builtin_amdgcn_mfma_f32_16x16x32_bf16(
            af[fr], bfr[fc], acc[fr][fc], 0, 0, 0);
    __syncthreads();
  }

  // epilogue: C/D layout col=lane&15, row=(lane>>4)*4+reg  [m89/m91-verified]
  float lsum = 0.f;
  int rq = (lane >> 4) * 4, cl = lane & 15;
  #pragma unroll
  for (int fr = 0; fr < 4; ++fr) {
    #pragma unroll
    for (int fc = 0; fc < 4; ++fc) {
      #pragma unroll
      for (int r = 0; r < 4; ++r) {
        float dot = acc[fr][fc][r];
        float l2 = sqR[wr + 16 * fr + rq + r] + sqC[wc + 16 * fc + cl] - 2.0f * dot;
        l2 = fmaxf(l2, 0.f);
        float w = __expf(cs * l2);      // w = exp(-L2/(16 bw0))
        float w2 = w * w, w4 = w2 * w2, w8 = w4 * w4, w16 = w8 * w8;
        lsum += w + w2 + w4 + w8 + w16;
      }
    }
  }
  double wt = (tr == tc) ? 1.0 : 2.0;
  if ((tr < 32) != (tc < 32)) wt = -wt;  // sign s_i*s_j is uniform per 128-tile
  double ds = (double)lsum * wt;
  #pragma unroll
  for (int off = 32; off; off >>= 1) ds += __shfl_down(ds, off);
  if (lane == 0) red[wave] = ds;
  __syncthreads();
  if (t == 0) atomicAdd(Sacc, red[0] + red[1] + red[2] + red[3]);
}

__global__ __launch_bounds__(64) void kfin(const double* __restrict__ Sacc,
                                           float* __restrict__ out) {
  if (threadIdx.x == 0) out[0] = (float)(Sacc[0] / (4096.0 * 4096.0));
}

extern "C" void kernel_launch(void* const* d_in, const int* in_sizes, int n_in,
                              void* d_out, int out_size, void* d_ws, size_t ws_size,
                              hipStream_t stream) {
  const float* src = (const float*)d_in[0];
  const float* tgt = (const float*)d_in[1];
  char* ws = (char*)d_ws;
  __bf16* Xbf = (__bf16*)ws;                                   // 8192*256*2 = 4 MiB
  float* sq   = (float*)(ws + 4194304);                        // 32 KiB
  double* accs = (double*)(ws + 4194304 + 32768);              // [0]=sum sq, [1]=sum colsum^2, [2]=S
  float* out = (float*)d_out;

  hipLaunchKernelGGL(kzero, dim3(1), dim3(64), 0, stream, accs);
  hipLaunchKernelGGL(kconv, dim3(2048), dim3(256), 0, stream, src, tgt, Xbf, sq, accs);
  hipLaunchKernelGGL(kcol, dim3(256), dim3(256), 0, stream, Xbf, accs);
  hipLaunchKernelGGL(kgemm, dim3(64, 64), dim3(256), 0, stream, Xbf, sq, accs, accs + 2);
  hipLaunchKernelGGL(kfin, dim3(1), dim3(64), 0, stream, accs + 2, out);
}

// Round 2
// 125.310 us; speedup vs baseline: 1.7973x; 1.7973x over previous
//
#include <hip/hip_runtime.h>
#include <hip/hip_bf16.h>
#include <stdint.h>

// MMD: N=8192 rows (4096 source + 4096 target), D=256, fp32 in, scalar fp32 out.
// result = (1/4096^2) * sum_ij s_i s_j ksum(L2_ij),  s_i = +1 (i<4096) else -1
// ksum = w + w^2 + w^4 + w^8 + w^16,  w = exp(-L2/(16 bw0))
// bw0 = [2N*sum(sq) - 2*sum_d colsum_d^2] / (N^2-N) / 4  (analytic sum(L2))
// R1 lesson: same-address fp64 atomics serialized kconv to 102us -> all
// reductions now go through scratch arrays + dedicated reduce kernels.

#define NTOT 8192
#define DDIM 256
#define TILE 128
#define BK 32

typedef __bf16 bf16x8 __attribute__((ext_vector_type(8)));
typedef __bf16 bf16x4 __attribute__((ext_vector_type(4)));
typedef float f32x4 __attribute__((ext_vector_type(4)));

__device__ __forceinline__ void gl_lds16(const __bf16* g, __bf16* l) {
  __builtin_amdgcn_global_load_lds(
      (const __attribute__((address_space(1))) void*)g,
      (__attribute__((address_space(3))) void*)l, 16, 0, 0);
}

// ---- fp32 -> bf16 convert + per-row sq + per-block column/sq partials (NO atomics) ----
__global__ __launch_bounds__(256) void kconv(const float* __restrict__ src,
                                             const float* __restrict__ tgt,
                                             __bf16* __restrict__ Xbf,
                                             float* __restrict__ sq,
                                             float* __restrict__ colpart,   // [256][256]
                                             float* __restrict__ sqpart) {  // [256]
  int b = blockIdx.x;           // 256 blocks, 32 rows each
  int t = threadIdx.x;
  int lane = t & 63, wave = t >> 6;
  float cp0 = 0.f, cp1 = 0.f, cp2 = 0.f, cp3 = 0.f;  // cols lane*4..+3
  float sqp = 0.f;                                   // lane-0 row-sq partial

  #pragma unroll
  for (int it = 0; it < 8; ++it) {
    int row = b * 32 + it * 4 + wave;
    const float* base = (row < 4096) ? (src + (size_t)row * DDIM)
                                     : (tgt + (size_t)(row - 4096) * DDIM);
    float4 v = ((const float4*)base)[lane];
    __bf16 b0 = (__bf16)v.x, b1 = (__bf16)v.y, b2 = (__bf16)v.z, b3 = (__bf16)v.w;
    bf16x4 pk = {b0, b1, b2, b3};
    ((bf16x4*)(Xbf + (size_t)row * DDIM))[lane] = pk;
    float f0 = (float)b0, f1 = (float)b1, f2 = (float)b2, f3 = (float)b3;
    cp0 += f0; cp1 += f1; cp2 += f2; cp3 += f3;
    float s = f0 * f0 + f1 * f1 + f2 * f2 + f3 * f3;
    #pragma unroll
    for (int off = 32; off; off >>= 1) s += __shfl_down(s, off);
    if (lane == 0) { sq[row] = s; sqp += s; }
  }

  // cross-wave column reduce via LDS
  __shared__ float cred[4][256];
  __shared__ float sred[4];
  ((float4*)&cred[wave][lane * 4])[0] = make_float4(cp0, cp1, cp2, cp3);
  if (lane == 0) sred[wave] = sqp;
  __syncthreads();
  float csum = cred[0][t] + cred[1][t] + cred[2][t] + cred[3][t];
  colpart[b * 256 + t] = csum;
  if (t == 0) sqpart[b] = sred[0] + sred[1] + sred[2] + sred[3];
}

// ---- single-block reduce: accs[0] = sum(sq), accs[1] = sum_d colsum_d^2 ----
__global__ __launch_bounds__(256) void kred(const float* __restrict__ colpart,
                                            const float* __restrict__ sqpart,
                                            double* __restrict__ accs) {
  int t = threadIdx.x;
  float csum = 0.f;
  for (int b = 0; b < 256; ++b) csum += colpart[b * 256 + t];  // coalesced across t
  __shared__ double r1[256], r2[256];
  r1[t] = (double)csum * (double)csum;
  r2[t] = (double)sqpart[t];
  __syncthreads();
  for (int off = 128; off; off >>= 1) {
    if (t < off) { r1[t] += r1[t + off]; r2[t] += r2[t + off]; }
    __syncthreads();
  }
  if (t == 0) { accs[1] = r1[0]; accs[0] = r2[0]; }
}

// ---- main: tiled symmetric Gram + fused kernel-sum epilogue, per-block Spart ----
__global__ __launch_bounds__(256) void kgemm(const __bf16* __restrict__ Xbf,
                                             const float* __restrict__ sq,
                                             const double* __restrict__ accs,
                                             double* __restrict__ Spart) {
  int tc = blockIdx.x, tr = blockIdx.y;
  int bid = tr * 64 + tc;
  int t = threadIdx.x;
  if (tr > tc) {                 // lower triangle: no work, but ws is poisoned ->
    if (t == 0) Spart[bid] = 0.0;  // must write a clean zero
    return;
  }

  __shared__ alignas(16) __bf16 Ash[TILE * BK];
  __shared__ alignas(16) __bf16 Bsh[TILE * BK];
  __shared__ float sqR[TILE], sqC[TILE];
  __shared__ double red[4];

  double ssq = accs[0], scol = accs[1];
  double sumL2 = 2.0 * 8192.0 * ssq - 2.0 * scol;
  double bw0 = sumL2 / (8192.0 * 8192.0 - 8192.0) / 4.0;
  float cs = (float)(-1.0 / (16.0 * bw0));

  if (t < 128) sqR[t] = sq[tr * TILE + t];
  else         sqC[t - 128] = sq[tc * TILE + (t - 128)];

  f32x4 acc[4][4];
  #pragma unroll
  for (int i = 0; i < 4; ++i)
    #pragma unroll
    for (int j = 0; j < 4; ++j) acc[i][j] = (f32x4){0.f, 0.f, 0.f, 0.f};

  const __bf16* Agbase = Xbf + (size_t)tr * TILE * DDIM;
  const __bf16* Bgbase = Xbf + (size_t)tc * TILE * DDIM;

  int wave = t >> 6, lane = t & 63;
  int mrow = lane & 15, kq = (lane >> 4) * 8;
  int wr = (wave & 1) * 64, wc = (wave >> 1) * 64;

  for (int it = 0; it < 8; ++it) {
    int k0 = it * BK;
    #pragma unroll
    for (int cc = 0; cc < 2; ++cc) {
      int c = t + cc * 256;
      int row = c >> 2, kc = c & 3;
      gl_lds16(Agbase + (size_t)row * DDIM + k0 + kc * 8, Ash + c * 8);
      gl_lds16(Bgbase + (size_t)row * DDIM + k0 + kc * 8, Bsh + c * 8);
    }
    __syncthreads();

    bf16x8 af[4], bfr[4];
    #pragma unroll
    for (int f = 0; f < 4; ++f) {
      af[f]  = *(const bf16x8*)&Ash[(wr + 16 * f + mrow) * BK + kq];
      bfr[f] = *(const bf16x8*)&Bsh[(wc + 16 * f + mrow) * BK + kq];
    }
    #pragma unroll
    for (int fr = 0; fr < 4; ++fr)
      #pragma unroll
      for (int fc = 0; fc < 4; ++fc)
        acc[fr][fc] = __builtin_amdgcn_mfma_f32_16x16x32_bf16(
            af[fr], bfr[fc], acc[fr][fc], 0, 0, 0);
    __syncthreads();
  }

  // epilogue: C/D layout col=lane&15, row=(lane>>4)*4+reg  [m89/m91-verified]
  float lsum = 0.f;
  int rq = (lane >> 4) * 4, cl = lane & 15;
  #pragma unroll
  for (int fr = 0; fr < 4; ++fr) {
    #pragma unroll
    for (int fc = 0; fc < 4; ++fc) {
      #pragma unroll
      for (int r = 0; r < 4; ++r) {
        float dot = acc[fr][fc][r];
        float l2 = sqR[wr + 16 * fr + rq + r] + sqC[wc + 16 * fc + cl] - 2.0f * dot;
        l2 = fmaxf(l2, 0.f);
        float w = __expf(cs * l2);
        float w2 = w * w, w4 = w2 * w2, w8 = w4 * w4, w16 = w8 * w8;
        lsum += w + w2 + w4 + w8 + w16;
      }
    }
  }
  double wt = (tr == tc) ? 1.0 : 2.0;
  if ((tr < 32) != (tc < 32)) wt = -wt;  // s_i*s_j uniform per 128-tile (4096/128=32)
  double ds = (double)lsum * wt;
  #pragma unroll
  for (int off = 32; off; off >>= 1) ds += __shfl_down(ds, off);
  if (lane == 0) red[wave] = ds;
  __syncthreads();
  if (t == 0) Spart[bid] = red[0] + red[1] + red[2] + red[3];
}

// ---- final reduce of 4096 per-block partials ----
__global__ __launch_bounds__(256) void kfin(const double* __restrict__ Spart,
                                            float* __restrict__ out) {
  int t = threadIdx.x;
  double s = 0.0;
  #pragma unroll
  for (int i = 0; i < 16; ++i) s += Spart[t + i * 256];
  __shared__ double red[256];
  red[t] = s;
  __syncthreads();
  for (int off = 128; off; off >>= 1) {
    if (t < off) red[t] += red[t + off];
    __syncthreads();
  }
  if (t == 0) out[0] = (float)(red[0] / (4096.0 * 4096.0));
}

extern "C" void kernel_launch(void* const* d_in, const int* in_sizes, int n_in,
                              void* d_out, int out_size, void* d_ws, size_t ws_size,
                              hipStream_t stream) {
  const float* src = (const float*)d_in[0];
  const float* tgt = (const float*)d_in[1];
  char* ws = (char*)d_ws;
  __bf16* Xbf    = (__bf16*)ws;                       // 4 MiB
  float* sq      = (float*)(ws + 4194304);            // 32 KiB
  float* colpart = (float*)(ws + 4227072);            // 256 KiB
  float* sqpart  = (float*)(ws + 4489216);            // 1 KiB
  double* accs   = (double*)(ws + 4490240);           // 16 B
  double* Spart  = (double*)(ws + 4490256);           // 32 KiB
  float* out = (float*)d_out;

  hipLaunchKernelGGL(kconv, dim3(256), dim3(256), 0, stream, src, tgt, Xbf, sq, colpart, sqpart);
  hipLaunchKernelGGL(kred, dim3(1), dim3(256), 0, stream, colpart, sqpart, accs);
  hipLaunchKernelGGL(kgemm, dim3(64, 64), dim3(256), 0, stream, Xbf, sq, accs, Spart);
  hipLaunchKernelGGL(kfin, dim3(1), dim3(256), 0, stream, Spart, out);
}

// Round 3
// 110.755 us; speedup vs baseline: 2.0335x; 1.1314x over previous
//
#include <hip/hip_runtime.h>
#include <hip/hip_bf16.h>
#include <stdint.h>
#include <math.h>

// MMD: N=8192 rows (4096 source + 4096 target), D=256, fp32 in, scalar fp32 out.
// result = (1/4096^2) * sum_ij s_i s_j ksum(L2_ij),  s_i = +1 (i<4096) else -1
// ksum = w + w^2 + w^4 + w^8 + w^16,  w = exp(-L2/(16 bw0))
// bw0 = [2N*sum(sq) - 2*sum_d colsum_d^2] / (N^2-N) / 4  (analytic sum(L2))
// R1: same-address fp64 atomics -> scratch arrays + reduce kernels.
// R2: 2.13M LDS bank conflicts (64B row stride -> 8-way) -> XOR swizzle of
//     16B chunks (global side of global_load_lds is per-lane gather; LDS side
//     stays lane-contiguous). Dead lower-triangle blocks -> triangular 1D
//     grid. No stage/compute overlap -> LDS double buffer with prefetch.

#define NTOT 8192
#define DDIM 256
#define TILE 128
#define BK 32
#define NBLK 2080  // 64*65/2 upper-triangle tiles

typedef __bf16 bf16x8 __attribute__((ext_vector_type(8)));
typedef __bf16 bf16x4 __attribute__((ext_vector_type(4)));
typedef float f32x4 __attribute__((ext_vector_type(4)));

__device__ __forceinline__ void gl_lds16(const __bf16* g, __bf16* l) {
  __builtin_amdgcn_global_load_lds(
      (const __attribute__((address_space(1))) void*)g,
      (__attribute__((address_space(3))) void*)l, 16, 0, 0);
}

// ---- fp32 -> bf16 convert + per-row sq + per-block column/sq partials ----
__global__ __launch_bounds__(256) void kconv(const float* __restrict__ src,
                                             const float* __restrict__ tgt,
                                             __bf16* __restrict__ Xbf,
                                             float* __restrict__ sq,
                                             float* __restrict__ colpart,   // [256][256]
                                             float* __restrict__ sqpart) {  // [256]
  int b = blockIdx.x;           // 256 blocks, 32 rows each
  int t = threadIdx.x;
  int lane = t & 63, wave = t >> 6;
  float cp0 = 0.f, cp1 = 0.f, cp2 = 0.f, cp3 = 0.f;
  float sqp = 0.f;

  #pragma unroll
  for (int it = 0; it < 8; ++it) {
    int row = b * 32 + it * 4 + wave;
    const float* base = (row < 4096) ? (src + (size_t)row * DDIM)
                                     : (tgt + (size_t)(row - 4096) * DDIM);
    float4 v = ((const float4*)base)[lane];
    __bf16 b0 = (__bf16)v.x, b1 = (__bf16)v.y, b2 = (__bf16)v.z, b3 = (__bf16)v.w;
    bf16x4 pk = {b0, b1, b2, b3};
    ((bf16x4*)(Xbf + (size_t)row * DDIM))[lane] = pk;
    float f0 = (float)b0, f1 = (float)b1, f2 = (float)b2, f3 = (float)b3;
    cp0 += f0; cp1 += f1; cp2 += f2; cp3 += f3;
    float s = f0 * f0 + f1 * f1 + f2 * f2 + f3 * f3;
    #pragma unroll
    for (int off = 32; off; off >>= 1) s += __shfl_down(s, off);
    if (lane == 0) { sq[row] = s; sqp += s; }
  }

  __shared__ float cred[4][256];
  __shared__ float sred[4];
  ((float4*)&cred[wave][lane * 4])[0] = make_float4(cp0, cp1, cp2, cp3);
  if (lane == 0) sred[wave] = sqp;
  __syncthreads();
  float csum = cred[0][t] + cred[1][t] + cred[2][t] + cred[3][t];
  colpart[b * 256 + t] = csum;
  if (t == 0) sqpart[b] = sred[0] + sred[1] + sred[2] + sred[3];
}

// ---- single-block reduce: accs[0] = sum(sq), accs[1] = sum_d colsum_d^2 ----
__global__ __launch_bounds__(256) void kred(const float* __restrict__ colpart,
                                            const float* __restrict__ sqpart,
                                            double* __restrict__ accs) {
  int t = threadIdx.x;
  float csum = 0.f;
  #pragma unroll 16
  for (int bb = 0; bb < 256; ++bb) csum += colpart[bb * 256 + t];
  __shared__ double r1[256], r2[256];
  r1[t] = (double)csum * (double)csum;
  r2[t] = (double)sqpart[t];
  __syncthreads();
  for (int off = 128; off; off >>= 1) {
    if (t < off) { r1[t] += r1[t + off]; r2[t] += r2[t + off]; }
    __syncthreads();
  }
  if (t == 0) { accs[1] = r1[0]; accs[0] = r2[0]; }
}

// ---- stage one 128x32 A-tile + B-tile into LDS with XOR-swizzled chunks ----
// chunk (row, kc) -> LDS slot row*4 + (kc ^ ((row>>1)&3)); global side is a
// per-lane gather, LDS side stays base + lane*16 (DMA constraint).
__device__ __forceinline__ void stage(const __bf16* __restrict__ Ab,
                                      const __bf16* __restrict__ Bb,
                                      int k0, __bf16* As, __bf16* Bs, int t) {
  #pragma unroll
  for (int cc = 0; cc < 2; ++cc) {
    int c = t + cc * 256;
    int row = c >> 2, kcs = c & 3;
    int kc = kcs ^ ((row >> 1) & 3);
    gl_lds16(Ab + (size_t)row * DDIM + k0 + kc * 8, As + c * 8);
    gl_lds16(Bb + (size_t)row * DDIM + k0 + kc * 8, Bs + c * 8);
  }
}

// ---- main: triangular-tiled Gram + fused kernel-sum epilogue ----
__global__ __launch_bounds__(256, 3) void kgemm(const __bf16* __restrict__ Xbf,
                                                const float* __restrict__ sq,
                                                const double* __restrict__ accs,
                                                double* __restrict__ Spart) {
  int b = blockIdx.x;  // 0..2079 upper-triangle linear index
  // decode (tr, tc): offset(tr) = tr*(129-tr)/2
  int tr = (int)((129.0 - sqrt(129.0 * 129.0 - 8.0 * (double)b)) * 0.5);
  while (tr > 0 && tr * (129 - tr) / 2 > b) --tr;
  while ((tr + 1) * (128 - tr) / 2 <= b) ++tr;
  int tc = tr + (b - tr * (129 - tr) / 2);

  __shared__ alignas(16) __bf16 Ash[2][TILE * BK];
  __shared__ alignas(16) __bf16 Bsh[2][TILE * BK];
  __shared__ float sqR[TILE], sqC[TILE];
  __shared__ double red[4];

  int t = threadIdx.x;

  double ssq = accs[0], scol = accs[1];
  double sumL2 = 2.0 * 8192.0 * ssq - 2.0 * scol;
  double bw0 = sumL2 / (8192.0 * 8192.0 - 8192.0) / 4.0;
  float cs = (float)(-1.0 / (16.0 * bw0));

  if (t < 128) sqR[t] = sq[tr * TILE + t];
  else         sqC[t - 128] = sq[tc * TILE + (t - 128)];

  f32x4 acc[4][4];
  #pragma unroll
  for (int i = 0; i < 4; ++i)
    #pragma unroll
    for (int j = 0; j < 4; ++j) acc[i][j] = (f32x4){0.f, 0.f, 0.f, 0.f};

  const __bf16* Agbase = Xbf + (size_t)tr * TILE * DDIM;
  const __bf16* Bgbase = Xbf + (size_t)tc * TILE * DDIM;

  int wave = t >> 6, lane = t & 63;
  int mrow = lane & 15, q = lane >> 4;
  int sw = (mrow >> 1) & 3;  // swizzle key depends only on row&15 (wr+16f = 0 mod 16)
  int wr = (wave & 1) * 64, wc = (wave >> 1) * 64;

  stage(Agbase, Bgbase, 0, Ash[0], Bsh[0], t);
  __syncthreads();

  for (int it = 0; it < 8; ++it) {
    int buf = it & 1;
    if (it < 7)  // prefetch next tile into other buffer; drain overlaps compute
      stage(Agbase, Bgbase, (it + 1) * BK, Ash[buf ^ 1], Bsh[buf ^ 1], t);

    bf16x8 af[4], bfr[4];
    #pragma unroll
    for (int f = 0; f < 4; ++f) {
      int rowA = wr + 16 * f + mrow;
      int rowB = wc + 16 * f + mrow;
      af[f]  = *(const bf16x8*)&Ash[buf][(rowA * 4 + (q ^ sw)) * 8];
      bfr[f] = *(const bf16x8*)&Bsh[buf][(rowB * 4 + (q ^ sw)) * 8];
    }
    #pragma unroll
    for (int fr = 0; fr < 4; ++fr)
      #pragma unroll
      for (int fc = 0; fc < 4; ++fc)
        acc[fr][fc] = __builtin_amdgcn_mfma_f32_16x16x32_bf16(
            af[fr], bfr[fc], acc[fr][fc], 0, 0, 0);
    __syncthreads();
  }

  // epilogue: C/D layout col=lane&15, row=(lane>>4)*4+reg  [m89/m91-verified]
  float lsum = 0.f;
  int rq = (lane >> 4) * 4, cl = lane & 15;
  #pragma unroll
  for (int fr = 0; fr < 4; ++fr) {
    #pragma unroll
    for (int fc = 0; fc < 4; ++fc) {
      #pragma unroll
      for (int r = 0; r < 4; ++r) {
        float dot = acc[fr][fc][r];
        float l2 = sqR[wr + 16 * fr + rq + r] + sqC[wc + 16 * fc + cl] - 2.0f * dot;
        l2 = fmaxf(l2, 0.f);
        float w = __expf(cs * l2);
        float w2 = w * w, w4 = w2 * w2, w8 = w4 * w4, w16 = w8 * w8;
        lsum += w + w2 + w4 + w8 + w16;
      }
    }
  }
  double wt = (tr == tc) ? 1.0 : 2.0;
  if ((tr < 32) != (tc < 32)) wt = -wt;  // s_i*s_j uniform per 128-tile
  double ds = (double)lsum * wt;
  #pragma unroll
  for (int off = 32; off; off >>= 1) ds += __shfl_down(ds, off);
  if (lane == 0) red[wave] = ds;
  __syncthreads();
  if (t == 0) Spart[b] = red[0] + red[1] + red[2] + red[3];
}

// ---- final reduce of 2080 per-block partials ----
__global__ __launch_bounds__(256) void kfin(const double* __restrict__ Spart,
                                            float* __restrict__ out) {
  int t = threadIdx.x;
  double s = 0.0;
  #pragma unroll
  for (int i = 0; i < 9; ++i) {
    int idx = t + i * 256;
    if (idx < NBLK) s += Spart[idx];
  }
  __shared__ double red[256];
  red[t] = s;
  __syncthreads();
  for (int off = 128; off; off >>= 1) {
    if (t < off) red[t] += red[t + off];
    __syncthreads();
  }
  if (t == 0) out[0] = (float)(red[0] / (4096.0 * 4096.0));
}

extern "C" void kernel_launch(void* const* d_in, const int* in_sizes, int n_in,
                              void* d_out, int out_size, void* d_ws, size_t ws_size,
                              hipStream_t stream) {
  const float* src = (const float*)d_in[0];
  const float* tgt = (const float*)d_in[1];
  char* ws = (char*)d_ws;
  __bf16* Xbf    = (__bf16*)ws;                       // 4 MiB
  float* sq      = (float*)(ws + 4194304);            // 32 KiB
  float* colpart = (float*)(ws + 4227072);            // 256 KiB
  float* sqpart  = (float*)(ws + 4489216);            // 1 KiB
  double* accs   = (double*)(ws + 4490240);           // 16 B
  double* Spart  = (double*)(ws + 4490256);           // 16.25 KiB
  float* out = (float*)d_out;

  hipLaunchKernelGGL(kconv, dim3(256), dim3(256), 0, stream, src, tgt, Xbf, sq, colpart, sqpart);
  hipLaunchKernelGGL(kred, dim3(1), dim3(256), 0, stream, colpart, sqpart, accs);
  hipLaunchKernelGGL(kgemm, dim3(NBLK), dim3(256), 0, stream, Xbf, sq, accs, Spart);
  hipLaunchKernelGGL(kfin, dim3(1), dim3(256), 0, stream, Spart, out);
}

// Round 4
// 103.626 us; speedup vs baseline: 2.1734x; 1.0688x over previous
//
#include <hip/hip_runtime.h>
#include <hip/hip_bf16.h>
#include <stdint.h>
#include <math.h>

// MMD: N=8192 rows (4096 source + 4096 target), D=256, fp32 in, scalar fp32 out.
// result = (1/4096^2) * sum_ij s_i s_j ksum(L2_ij),  s_i = +1 (i<4096) else -1
// ksum = w + w^2 + w^4 + w^8 + w^16,  w = exp(-L2/(16 bw0))
// bw0 = [2N*sum(sq) - 2*sum_d colsum_d^2] / (N^2-N) / 4  (analytic sum(L2))
// R1: same-address fp64 atomics -> scratch arrays + reduce kernels.
// R2: LDS bank conflicts -> XOR chunk swizzle; triangular grid; dbuf.
// R3: top dispatch is the harness's 256MB 0xAA ws poison-fill (43us, fixed
//     floor). Attack kgemm: MX-fp8 K=128 MFMA (scale=1) -> 4x fewer MFMA,
//     half the LDS bytes, whole-K staged once (one barrier, no K-loop).
//     A/B use identical lane->k maps so any internal k-permutation cancels
//     in the dot; C/D layout is shape-determined (16x16, m121-128).

#define NTOT 8192
#define DDIM 256
#define TILE 128
#define NBLK 2080  // 64*65/2 upper-triangle tiles

typedef int i32x8 __attribute__((ext_vector_type(8)));
typedef int i32x4 __attribute__((ext_vector_type(4)));
typedef float f32x4 __attribute__((ext_vector_type(4)));

__device__ __forceinline__ void gl_lds16(const void* g, void* l) {
  __builtin_amdgcn_global_load_lds(
      (const __attribute__((address_space(1))) void*)g,
      (__attribute__((address_space(3))) void*)l, 16, 0, 0);
}

// ---- fp32 -> fp8(e4m3, OCP) convert + per-row sq + per-block partials ----
__global__ __launch_bounds__(256) void kconv(const float* __restrict__ src,
                                             const float* __restrict__ tgt,
                                             unsigned char* __restrict__ X8,
                                             float* __restrict__ sq,
                                             float* __restrict__ colpart,   // [256][256]
                                             float* __restrict__ sqpart) {  // [256]
  int b = blockIdx.x;           // 256 blocks, 32 rows each
  int t = threadIdx.x;
  int lane = t & 63, wave = t >> 6;
  float cp0 = 0.f, cp1 = 0.f, cp2 = 0.f, cp3 = 0.f;
  float sqp = 0.f;

  #pragma unroll
  for (int it = 0; it < 8; ++it) {
    int row = b * 32 + it * 4 + wave;
    const float* base = (row < 4096) ? (src + (size_t)row * DDIM)
                                     : (tgt + (size_t)(row - 4096) * DDIM);
    float4 v = ((const float4*)base)[lane];
    int p = __builtin_amdgcn_cvt_pk_fp8_f32(v.x, v.y, 0, false);
    p = __builtin_amdgcn_cvt_pk_fp8_f32(v.z, v.w, p, true);
    ((int*)(X8 + (size_t)row * DDIM))[lane] = p;
    // read back the fp8-rounded values (sq/bw0 must match kgemm's dots)
    float f0 = __builtin_amdgcn_cvt_f32_fp8(p, 0);
    float f1 = __builtin_amdgcn_cvt_f32_fp8(p, 1);
    float f2 = __builtin_amdgcn_cvt_f32_fp8(p, 2);
    float f3 = __builtin_amdgcn_cvt_f32_fp8(p, 3);
    cp0 += f0; cp1 += f1; cp2 += f2; cp3 += f3;
    float s = f0 * f0 + f1 * f1 + f2 * f2 + f3 * f3;
    #pragma unroll
    for (int off = 32; off; off >>= 1) s += __shfl_down(s, off);
    if (lane == 0) { sq[row] = s; sqp += s; }
  }

  __shared__ float cred[4][256];
  __shared__ float sred[4];
  ((float4*)&cred[wave][lane * 4])[0] = make_float4(cp0, cp1, cp2, cp3);
  if (lane == 0) sred[wave] = sqp;
  __syncthreads();
  float csum = cred[0][t] + cred[1][t] + cred[2][t] + cred[3][t];
  colpart[b * 256 + t] = csum;
  if (t == 0) sqpart[b] = sred[0] + sred[1] + sred[2] + sred[3];
}

// ---- single-block reduce: accs[0] = sum(sq), accs[1] = sum_d colsum_d^2 ----
__global__ __launch_bounds__(256) void kred(const float* __restrict__ colpart,
                                            const float* __restrict__ sqpart,
                                            double* __restrict__ accs) {
  int t = threadIdx.x;
  float csum = 0.f;
  #pragma unroll 16
  for (int bb = 0; bb < 256; ++bb) csum += colpart[bb * 256 + t];
  __shared__ double r1[256], r2[256];
  r1[t] = (double)csum * (double)csum;
  r2[t] = (double)sqpart[t];
  __syncthreads();
  for (int off = 128; off; off >>= 1) {
    if (t < off) { r1[t] += r1[t + off]; r2[t] += r2[t + off]; }
    __syncthreads();
  }
  if (t == 0) { accs[1] = r1[0]; accs[0] = r2[0]; }
}

// ---- main: triangular-tiled Gram (MX-fp8 K=128) + fused kernel-sum ----
// Stage full 128x256 fp8 A,B tiles (32 KB each) with 16B chunks at LDS slot
// row*16 + (kc ^ (row&15))  [swizzle breaks the 256B-row-stride 16-way
// bank conflict; 2-way residue is free per m136].
__global__ __launch_bounds__(256, 2) void kgemm(const unsigned char* __restrict__ X8,
                                                const float* __restrict__ sq,
                                                const double* __restrict__ accs,
                                                double* __restrict__ Spart) {
  int b = blockIdx.x;  // 0..2079 upper-triangle linear index
  int tr = (int)((129.0 - sqrt(129.0 * 129.0 - 8.0 * (double)b)) * 0.5);
  while (tr > 0 && tr * (129 - tr) / 2 > b) --tr;
  while ((tr + 1) * (128 - tr) / 2 <= b) ++tr;
  int tc = tr + (b - tr * (129 - tr) / 2);

  __shared__ alignas(16) unsigned char Ash[TILE * DDIM];  // 32 KB
  __shared__ alignas(16) unsigned char Bsh[TILE * DDIM];  // 32 KB
  __shared__ float sqR[TILE], sqC[TILE];
  __shared__ double red[4];

  int t = threadIdx.x;

  double ssq = accs[0], scol = accs[1];
  double sumL2 = 2.0 * 8192.0 * ssq - 2.0 * scol;
  double bw0 = sumL2 / (8192.0 * 8192.0 - 8192.0) / 4.0;
  float cs = (float)(-1.0 / (16.0 * bw0));

  const unsigned char* Ag = X8 + (size_t)tr * TILE * DDIM;
  const unsigned char* Bg = X8 + (size_t)tc * TILE * DDIM;
  bool diag = (tr == tc);

  // stage: 2048 16B chunks per tile, 8 per thread (+8 for B unless diagonal)
  #pragma unroll
  for (int cc = 0; cc < 8; ++cc) {
    int c = t + cc * 256;
    int row = c >> 4, kcs = c & 15;
    int kc = kcs ^ (row & 15);
    gl_lds16(Ag + (size_t)row * DDIM + kc * 16, Ash + c * 16);
  }
  if (!diag) {
    #pragma unroll
    for (int cc = 0; cc < 8; ++cc) {
      int c = t + cc * 256;
      int row = c >> 4, kcs = c & 15;
      int kc = kcs ^ (row & 15);
      gl_lds16(Bg + (size_t)row * DDIM + kc * 16, Bsh + c * 16);
    }
  }
  if (t < 128) sqR[t] = sq[tr * TILE + t];
  else         sqC[t - 128] = sq[tc * TILE + (t - 128)];
  __syncthreads();

  const unsigned char* Bs = diag ? Ash : Bsh;

  f32x4 acc[4][4];
  #pragma unroll
  for (int i = 0; i < 4; ++i)
    #pragma unroll
    for (int j = 0; j < 4; ++j) acc[i][j] = (f32x4){0.f, 0.f, 0.f, 0.f};

  int wave = t >> 6, lane = t & 63;
  int mrow = lane & 15, q = lane >> 4;
  int wr = (wave & 1) * 64, wc = (wave >> 1) * 64;
  const int sone = 0x7F7F7F7F;  // e8m0 scale = 1.0 in every byte

  #pragma unroll
  for (int ki = 0; ki < 2; ++ki) {
    int kc0 = ki * 8 + q * 2;  // even 16B-chunk index within the row
    i32x8 af[4], bf[4];
    #pragma unroll
    for (int f = 0; f < 4; ++f) {
      int rowA = wr + 16 * f + mrow;
      int rowB = wc + 16 * f + mrow;
      i32x4 alo = *(const i32x4*)&Ash[rowA * DDIM + (kc0 ^ mrow) * 16];
      i32x4 ahi = *(const i32x4*)&Ash[rowA * DDIM + ((kc0 + 1) ^ mrow) * 16];
      i32x4 blo = *(const i32x4*)&Bs[rowB * DDIM + (kc0 ^ mrow) * 16];
      i32x4 bhi = *(const i32x4*)&Bs[rowB * DDIM + ((kc0 + 1) ^ mrow) * 16];
      af[f] = (i32x8){alo.x, alo.y, alo.z, alo.w, ahi.x, ahi.y, ahi.z, ahi.w};
      bf[f] = (i32x8){blo.x, blo.y, blo.z, blo.w, bhi.x, bhi.y, bhi.z, bhi.w};
    }
    #pragma unroll
    for (int fr = 0; fr < 4; ++fr)
      #pragma unroll
      for (int fc = 0; fc < 4; ++fc)
        acc[fr][fc] = __builtin_amdgcn_mfma_scale_f32_16x16x128_f8f6f4(
            af[fr], bf[fc], acc[fr][fc], 0, 0, 0, sone, 0, sone);
  }

  // epilogue: C/D layout col=lane&15, row=(lane>>4)*4+reg  [m89/m91; dtype-indep]
  float lsum = 0.f;
  int rq = q * 4, cl = mrow;
  #pragma unroll
  for (int fr = 0; fr < 4; ++fr) {
    #pragma unroll
    for (int fc = 0; fc < 4; ++fc) {
      #pragma unroll
      for (int r = 0; r < 4; ++r) {
        float dot = acc[fr][fc][r];
        float l2 = sqR[wr + 16 * fr + rq + r] + sqC[wc + 16 * fc + cl] - 2.0f * dot;
        l2 = fmaxf(l2, 0.f);
        float w = __expf(cs * l2);
        float w2 = w * w, w4 = w2 * w2, w8 = w4 * w4, w16 = w8 * w8;
        lsum += w + w2 + w4 + w8 + w16;
      }
    }
  }
  double wt = diag ? 1.0 : 2.0;
  if ((tr < 32) != (tc < 32)) wt = -wt;  // s_i*s_j uniform per 128-tile
  double ds = (double)lsum * wt;
  #pragma unroll
  for (int off = 32; off; off >>= 1) ds += __shfl_down(ds, off);
  if (lane == 0) red[wave] = ds;
  __syncthreads();
  if (t == 0) Spart[b] = red[0] + red[1] + red[2] + red[3];
}

// ---- final reduce of 2080 per-block partials ----
__global__ __launch_bounds__(256) void kfin(const double* __restrict__ Spart,
                                            float* __restrict__ out) {
  int t = threadIdx.x;
  double s = 0.0;
  #pragma unroll
  for (int i = 0; i < 9; ++i) {
    int idx = t + i * 256;
    if (idx < NBLK) s += Spart[idx];
  }
  __shared__ double red[256];
  red[t] = s;
  __syncthreads();
  for (int off = 128; off; off >>= 1) {
    if (t < off) red[t] += red[t + off];
    __syncthreads();
  }
  if (t == 0) out[0] = (float)(red[0] / (4096.0 * 4096.0));
}

extern "C" void kernel_launch(void* const* d_in, const int* in_sizes, int n_in,
                              void* d_out, int out_size, void* d_ws, size_t ws_size,
                              hipStream_t stream) {
  const float* src = (const float*)d_in[0];
  const float* tgt = (const float*)d_in[1];
  char* ws = (char*)d_ws;
  unsigned char* X8 = (unsigned char*)ws;             // 8192*256 = 2 MiB
  float* sq      = (float*)(ws + 2097152);            // 32 KiB
  float* colpart = (float*)(ws + 2129920);            // 256 KiB
  float* sqpart  = (float*)(ws + 2392064);            // 1 KiB
  double* accs   = (double*)(ws + 2393088);           // 16 B
  double* Spart  = (double*)(ws + 2393104);           // 16.25 KiB
  float* out = (float*)d_out;

  hipLaunchKernelGGL(kconv, dim3(256), dim3(256), 0, stream, src, tgt, X8, sq, colpart, sqpart);
  hipLaunchKernelGGL(kred, dim3(1), dim3(256), 0, stream, colpart, sqpart, accs);
  hipLaunchKernelGGL(kgemm, dim3(NBLK), dim3(256), 0, stream, X8, sq, accs, Spart);
  hipLaunchKernelGGL(kfin, dim3(1), dim3(256), 0, stream, Spart, out);
}